// Round 9
// baseline (929.071 us; speedup 1.0000x reference)
//
#include <hip/hip_runtime.h>
#include <math.h>

constexpr int GG  = 1024;   // graphs
constexpr int NN  = 256;    // nodes layer0
constexpr int FF  = 128;    // input feat
constexpr int DD  = 256;    // hidden
constexpr int KS0 = 32, KS1 = 16, KS2 = 8;

__device__ __forceinline__ float lrelu(float x){ return x >= 0.f ? x : 0.01f*x; }

// bf16 helpers
__device__ __forceinline__ unsigned short f2bf(float f) {
  unsigned u = __float_as_uint(f);
  unsigned r = (u + 0x7FFFu + ((u >> 16) & 1u)) >> 16;
  return (unsigned short)r;
}
__device__ __forceinline__ float bf2f(unsigned short h) {
  return __uint_as_float(((unsigned)h) << 16);
}

typedef __attribute__((ext_vector_type(8)))  __bf16 bf16x8;
typedef __attribute__((ext_vector_type(16))) float  f32x16;

union Frag8 { unsigned short us[8]; unsigned long long u64[2]; bf16x8 v; };

// ---------------- pre-split all 3 weights into 3 bf16 planes, frag-blocked kti-major ----------------
__global__ void k_splitW_all(const float* __restrict__ Wa, const float* __restrict__ Wb,
                             const float* __restrict__ Wc,
                             unsigned short* __restrict__ oa, unsigned short* __restrict__ ob,
                             unsigned short* __restrict__ oc) {
  int e = blockIdx.x*256 + threadIdx.x;
  if (e >= FF*DD + 2*DD*DD) return;
  const float* W; unsigned short* out; int K;
  if (e < FF*DD)                { W = Wa; out = oa; K = FF; }
  else if (e < FF*DD + DD*DD)   { e -= FF*DD; W = Wb; out = ob; K = DD; }
  else                          { e -= FF*DD + DD*DD; W = Wc; out = oc; K = DD; }
  int j    = e & 7;
  int lane = (e >> 3) & 63;
  int nt   = (e >> 9) & 7;
  int s    = (e >> 12) & 1;
  int kti  = e >> 13;
  int n = nt*32 + (lane & 31);
  int k = kti*32 + s*16 + ((lane >> 5) << 3) + j;
  float x = W[(size_t)k*DD + n];
  unsigned short h1 = f2bf(x);  float r1 = x - bf2f(h1);
  unsigned short h2 = f2bf(r1); float r2 = r1 - bf2f(h2);
  unsigned short h3 = f2bf(r2);
  out[e] = h1; out[DD*K + e] = h2; out[2*DD*K + e] = h3;
}

// ---------------- mask + norm: wave per row; 4 x ballot -> 256-bit row mask ----------------
__global__ void k_maskrow(const float* __restrict__ adj, float* __restrict__ norm0,
                          unsigned long long* __restrict__ mask) {
  int row = blockIdx.x*4 + (threadIdx.x >> 6);
  int lane = threadIdx.x & 63;
  const float* ar = adj + (size_t)row*NN;
  float f0 = ar[lane], f1 = ar[64 + lane], f2 = ar[128 + lane], f3 = ar[192 + lane];
  unsigned long long m0 = __ballot(f0 > 0.5f);
  unsigned long long m1 = __ballot(f1 > 0.5f);
  unsigned long long m2 = __ballot(f2 > 0.5f);
  unsigned long long m3 = __ballot(f3 > 0.5f);
  if (lane < 4) {
    unsigned long long mm = lane == 0 ? m0 : lane == 1 ? m1 : lane == 2 ? m2 : m3;
    mask[(size_t)row*4 + lane] = mm;
  }
  if (lane == 0) {
    int cnt = __popcll(m0) + __popcll(m1) + __popcll(m2) + __popcll(m3);
    norm0[row] = rsqrtf(fmaxf((float)cnt, 1.0f));
  }
}

// ---------------- sparse spmm: degree-sorted gather (per-block counting sort) ----------------
// grid = 4*GG; block (g,q) computes 256 rows x 32 cols. Rows are counting-sorted by degree so
// each wave's exec-masked gather loop runs ~its own max degree (saves ~21% of ds_read issue).
// The permutation is numerics-invariant: each row's sum order (w asc, ctz asc) is unchanged;
// outputs are shuffled back through LDS so global writes stay row-ordered/coalesced.
__global__ __launch_bounds__(256, 4) void k_spmm_s(
    const float* __restrict__ feat, const unsigned long long* __restrict__ mask,
    const float* __restrict__ norm0, float* __restrict__ T0) {
  constexpr int ST = 36;                  // floats; rows 144 B, 16B-aligned
  __shared__ float ls[NN*ST];             // 36864 B (also sort scratch before staging)
  __shared__ float snorm[NN];
  int bid = blockIdx.x;
  int g = bid >> 2, q = bid & 3;
  int t = threadIdx.x;
  const float* Xg = feat + (size_t)g*NN*FF + q*32;

  // ---- counting sort by degree (scratch overlays ls; done before staging) ----
  int* hist = reinterpret_cast<int*>(ls);        // [256]
  int* bs   = hist + 256;                        // [256] exclusive bin base
  int* prm  = hist + 512;                        // [256] rank -> row
  {
    const unsigned long long* mp = mask + ((size_t)g*NN + t)*4;
    unsigned long long m0 = mp[0], m1 = mp[1], m2 = mp[2], m3 = mp[3];
    int deg = __popcll(m0) + __popcll(m1) + __popcll(m2) + __popcll(m3);
    snorm[t] = norm0[g*NN + t];
    hist[t] = 0;
    __syncthreads();
    atomicAdd(&hist[deg], 1);
    __syncthreads();
    if (t < 64) {
      int h0 = hist[4*t], h1 = hist[4*t+1], h2 = hist[4*t+2], h3 = hist[4*t+3];
      int s = h0 + h1 + h2 + h3;
      int incl = s;
      #pragma unroll
      for (int off = 1; off < 64; off <<= 1) {
        int o = __shfl_up(incl, off);
        if (t >= off) incl += o;
      }
      int excl = incl - s;
      bs[4*t]   = excl;
      bs[4*t+1] = excl + h0;
      bs[4*t+2] = excl + h0 + h1;
      bs[4*t+3] = excl + h0 + h1 + h2;
    }
    __syncthreads();
    int old = atomicSub(&hist[deg], 1);
    prm[bs[deg] + old - 1] = t;
  }
  __syncthreads();
  int row = prm[t];                       // this thread gathers row 'row'
  __syncthreads();                        // ls scratch free

  // issue perm-row mask loads early (latency hides under staging)
  const unsigned long long* mr = mask + ((size_t)g*NN + row)*4;
  unsigned long long n0 = mr[0], n1 = mr[1], n2 = mr[2], n3 = mr[3];

  // ---- stage 256 rows x 32 cols of X*norm into LDS ----
  #pragma unroll
  for (int i = 0; i < 8; ++i) {
    int e = t + i*256;
    int r = e >> 3, c4 = (e & 7)*4;
    float4 v = *reinterpret_cast<const float4*>(Xg + (size_t)r*FF + c4);
    float nv = snorm[r];
    v.x *= nv; v.y *= nv; v.z *= nv; v.w *= nv;
    *reinterpret_cast<float4*>(&ls[r*ST + c4]) = v;
  }
  __syncthreads();

  // ---- gather: ascending neighbor index (matches dense einsum order exactly) ----
  float4 acc[8];
  #pragma unroll
  for (int i = 0; i < 8; ++i) acc[i] = make_float4(0.f, 0.f, 0.f, 0.f);
  #pragma unroll
  for (int w = 0; w < 4; ++w) {
    unsigned long long m = w == 0 ? n0 : w == 1 ? n1 : w == 2 ? n2 : n3;
    while (m) {
      int c = __builtin_ctzll(m);
      const float4* xp = reinterpret_cast<const float4*>(&ls[(w*64 + c)*ST]);
      #pragma unroll
      for (int i = 0; i < 8; ++i) {
        float4 v = xp[i];
        acc[i].x += v.x; acc[i].y += v.y; acc[i].z += v.z; acc[i].w += v.w;
      }
      m &= m - 1;
    }
  }
  __syncthreads();                        // all staged reads complete

  // ---- shuffle results back to row order through LDS; coalesced global writes ----
  #pragma unroll
  for (int i = 0; i < 8; ++i)
    *reinterpret_cast<float4*>(&ls[row*ST + i*4]) = acc[i];
  __syncthreads();
  float* op = T0 + ((size_t)g*NN + t)*FF + q*32;
  #pragma unroll
  for (int i = 0; i < 8; ++i)
    *reinterpret_cast<float4*>(op + i*4) = *reinterpret_cast<const float4*>(&ls[t*ST + i*4]);
}

// ---------------- layer0 GEMM: 4-wave blocks, B read DIRECT from global (L2-hot, no barriers) ----------------
__global__ __launch_bounds__(256, 2) void k_gemm0(
    const float* __restrict__ Tmat, const unsigned short* __restrict__ Wk,
    const float* __restrict__ normv, const float* __restrict__ bias,
    const float* __restrict__ Ws, float* __restrict__ hs) {
  int t = threadIdx.x;
  int lane = t & 63, wave = t >> 6;
  int lm = lane & 31, lh = lane >> 5;
  int rowbase = blockIdx.x*128 + wave*32;

  f32x16 acc[8];
  #pragma unroll
  for (int nt = 0; nt < 8; ++nt) acc[nt] = (f32x16)0.0f;

  for (int kti = 0; kti < 4; ++kti) {
    int kt = kti*32;
    float4 af[2][2];
    #pragma unroll
    for (int s = 0; s < 2; ++s) {
      const float* ap = Tmat + (size_t)(rowbase + lm)*FF + kt + s*16 + lh*8;
      af[s][0] = *reinterpret_cast<const float4*>(ap);
      af[s][1] = *reinterpret_cast<const float4*>(ap + 4);
    }
    Frag8 afr[2][3];
    #pragma unroll
    for (int s = 0; s < 2; ++s) {
      const float* fv = &af[s][0].x;
      #pragma unroll
      for (int j = 0; j < 8; ++j) {
        float x = fv[j];
        unsigned short h1 = f2bf(x);  float r1 = x - bf2f(h1);
        unsigned short h2 = f2bf(r1); float r2 = r1 - bf2f(h2);
        afr[s][0].us[j] = h1; afr[s][1].us[j] = h2; afr[s][2].us[j] = f2bf(r2);
      }
    }
    #pragma unroll
    for (int s = 0; s < 2; ++s)
      #pragma unroll
      for (int nt = 0; nt < 8; ++nt) {
        size_t boff = ((((size_t)kti*2 + s)*8 + nt)*64 + lane)*8;
        Frag8 b0_, b1_, b2_;
        b0_.v = *reinterpret_cast<const bf16x8*>(Wk + boff);
        b1_.v = *reinterpret_cast<const bf16x8*>(Wk + (size_t)DD*FF + boff);
        b2_.v = *reinterpret_cast<const bf16x8*>(Wk + (size_t)2*DD*FF + boff);
        acc[nt] = __builtin_amdgcn_mfma_f32_32x32x16_bf16(afr[s][0].v, b0_.v, acc[nt], 0,0,0);
        acc[nt] = __builtin_amdgcn_mfma_f32_32x32x16_bf16(afr[s][0].v, b1_.v, acc[nt], 0,0,0);
        acc[nt] = __builtin_amdgcn_mfma_f32_32x32x16_bf16(afr[s][1].v, b0_.v, acc[nt], 0,0,0);
        acc[nt] = __builtin_amdgcn_mfma_f32_32x32x16_bf16(afr[s][0].v, b2_.v, acc[nt], 0,0,0);
        acc[nt] = __builtin_amdgcn_mfma_f32_32x32x16_bf16(afr[s][2].v, b0_.v, acc[nt], 0,0,0);
        acc[nt] = __builtin_amdgcn_mfma_f32_32x32x16_bf16(afr[s][1].v, b1_.v, acc[nt], 0,0,0);
      }
  }

  float bcol[8], wcol[8];
  #pragma unroll
  for (int nt = 0; nt < 8; ++nt) { int col = nt*32 + lm; bcol[nt] = bias[col]; wcol[nt] = Ws[col]; }
  float hsum[16];
  #pragma unroll
  for (int r = 0; r < 16; ++r) {
    int row = rowbase + (r & 3) + 8*(r >> 2) + 4*lh;
    float nv = normv[row];
    float hp = 0.f;
    #pragma unroll
    for (int nt = 0; nt < 8; ++nt) hp += lrelu(nv*acc[nt][r] + bcol[nt])*wcol[nt];
    hsum[r] = hp;
  }
  #pragma unroll
  for (int off = 1; off <= 16; off <<= 1)
    #pragma unroll
    for (int r = 0; r < 16; ++r) hsum[r] += __shfl_xor(hsum[r], off);
  if (lm == 0)
    #pragma unroll
    for (int r = 0; r < 16; ++r) {
      int row = rowbase + (r & 3) + 8*(r >> 2) + 4*lh;
      hs[row] = normv[row]*hsum[r];
    }
}

// ---------------- layer0: score + top-k + selection fused (per graph) ----------------
__global__ __launch_bounds__(256) void k_topk_sel0(
    const unsigned long long* __restrict__ mask, const float* __restrict__ hs,
    const float* __restrict__ norm0, const float* __restrict__ bs,
    const float* __restrict__ T0, const float* __restrict__ W0,
    const float* __restrict__ b0, float* __restrict__ x_sel,
    float* __restrict__ a1, float* __restrict__ merged) {
  __shared__ float sh[NN];
  __shared__ float ssc[NN];
  __shared__ float sT[KS0*FF];     // 16 KB
  __shared__ int sidx[KS0]; __shared__ float stv[KS0]; __shared__ float snv[KS0];
  int g = blockIdx.x, t = threadIdx.x;

  sh[t] = hs[g*NN + t];
  __syncthreads();
  const unsigned long long* mr = mask + ((size_t)g*NN + t)*4;
  float s = 0.f;
  #pragma unroll
  for (int w = 0; w < 4; ++w) {
    unsigned long long m = mr[w];
    const float* base = sh + w*64;
    while (m) {
      int c = __builtin_ctzll(m);
      s += base[c];
      m &= m - 1;
    }
  }
  ssc[t] = norm0[g*NN + t]*s + bs[0];
  __syncthreads();
  if (t < 64) {
    float sv[4]; int si[4];
    #pragma unroll
    for (int e = 0; e < 4; ++e) { sv[e] = ssc[e*64 + t]; si[e] = e*64 + t; }
    for (int kk = 0; kk < KS0; ++kk) {
      float bs_ = -INFINITY; int bi = 1 << 30;
      #pragma unroll
      for (int e = 0; e < 4; ++e)
        if (sv[e] > bs_ || (sv[e] == bs_ && si[e] < bi)) { bs_ = sv[e]; bi = si[e]; }
      for (int off = 32; off; off >>= 1) {
        float os = __shfl_xor(bs_, off);
        int oi = __shfl_xor(bi, off);
        if (os > bs_ || (os == bs_ && oi < bi)) { bs_ = os; bi = oi; }
      }
      if (t == 0) { sidx[kk] = bi; stv[kk] = tanhf(bs_); }
      #pragma unroll
      for (int e = 0; e < 4; ++e) if (si[e] == bi) sv[e] = -INFINITY;
    }
  }
  __syncthreads();
  // selection: recompute x1 rows for top-32, gate, readout, a1 from mask
  if (t < KS0) snv[t] = norm0[g*NN + sidx[t]];
  #pragma unroll
  for (int i = 0; i < 4; ++i) {
    int e4 = t + i*256;
    int r = e4 >> 5, c4 = e4 & 31;
    reinterpret_cast<float4*>(sT)[e4] =
        *reinterpret_cast<const float4*>(&T0[((size_t)g*NN + sidx[r])*FF + c4*4]);
  }
  __syncthreads();
  float sum[KS0];
  #pragma unroll
  for (int j = 0; j < KS0; ++j) sum[j] = 0.f;
  for (int k = 0; k < FF; k += 4) {
    float4 w;
    w.x = W0[(size_t)(k+0)*DD + t]; w.y = W0[(size_t)(k+1)*DD + t];
    w.z = W0[(size_t)(k+2)*DD + t]; w.w = W0[(size_t)(k+3)*DD + t];
    #pragma unroll
    for (int j = 0; j < KS0; ++j) {
      float4 tv4 = *reinterpret_cast<const float4*>(&sT[j*FF + k]);
      sum[j] += tv4.x*w.x + tv4.y*w.y + tv4.z*w.z + tv4.w*w.w;
    }
  }
  float b = b0[t];
  float ssum = 0.f, mx = -INFINITY;
  #pragma unroll
  for (int j = 0; j < KS0; ++j) {
    float val = lrelu(snv[j]*sum[j] + b) * stv[j];
    x_sel[((size_t)g*KS0 + j)*DD + t] = val;
    ssum += val; mx = fmaxf(mx, val);
  }
  merged[(size_t)g*1536 + t] = ssum;
  merged[(size_t)g*1536 + 256 + t] = mx;
  for (int e = t; e < KS0*KS0; e += 256) {
    int r = e >> 5, c = e & 31;
    int nr = sidx[r], nc = sidx[c];
    unsigned long long m = mask[((size_t)g*NN + nr)*4 + (nc >> 6)];
    a1[(size_t)g*KS0*KS0 + e] = (float)((m >> (nc & 63)) & 1ull);
  }
}

// ---------------- layer1 fully fused: norm + spmm + GEMM + score + topk + pool (per graph) ----------------
__global__ __launch_bounds__(256, 2) void k_fused1(
    const float* __restrict__ a, const float* __restrict__ xin,
    const unsigned short* __restrict__ Wk, const float* __restrict__ bias,
    const float* __restrict__ Ws, const float* __restrict__ bs,
    float* __restrict__ x_sel_out, float* __restrict__ a_out,
    float* __restrict__ merged) {
  constexpr int n = KS0;     // 32 nodes in
  constexpr int kp = KS1;    // 16 kept
  constexpr int TP = DD + 4; // padded LDS k-stride for T (260 floats, 16B-aligned rows)
  __shared__ float sa[n*n];          // 4 KB
  __shared__ float bufA[n*DD];       // 32 KB: x*norm, then x2
  __shared__ float sT[n*TP];         // 32.5 KB
  __shared__ float snorm[n]; __shared__ float shs[n]; __shared__ float ssc[n];
  __shared__ int sidx[kp]; __shared__ float stv[kp];
  int g = blockIdx.x, t = threadIdx.x;
  int lane = t & 63, wave = t >> 6, lm = lane & 31, lh = lane >> 5;

  for (int e = t; e < n*n; e += 256) sa[e] = a[(size_t)g*n*n + e];
  __syncthreads();
  if (t < n) {
    float dg = 0.f;
    for (int m = 0; m < n; ++m) dg += sa[m*n + t];   // a symmetric: == sa[t*n+m]
    snorm[t] = rsqrtf(fmaxf(dg, 1.f));
  }
  __syncthreads();
  {
    const float4* xp = reinterpret_cast<const float4*>(xin + (size_t)g*n*DD);
    #pragma unroll
    for (int i = 0; i < (n*DD/4)/256; ++i) {
      int e4 = t + i*256;
      float4 v = xp[e4];
      float nv = snorm[e4 >> 6];
      v.x *= nv; v.y *= nv; v.z *= nv; v.w *= nv;
      reinterpret_cast<float4*>(bufA)[e4] = v;
    }
  }
  __syncthreads();
  { // T = sa @ bufA ; thread t owns column t
    float acc2[n];
    #pragma unroll
    for (int r = 0; r < n; ++r) acc2[r] = 0.f;
    for (int m = 0; m < n; ++m) {
      float xv = bufA[m*DD + t];
      #pragma unroll
      for (int r = 0; r < n; ++r) acc2[r] += sa[r*n + m]*xv;
    }
    #pragma unroll
    for (int r = 0; r < n; ++r) sT[r*TP + t] = acc2[r];
  }
  __syncthreads();

  // GEMM: wave handles 64 cols (2 col-tiles); rows = all 32
  f32x16 acc[2];
  acc[0] = (f32x16)0.0f; acc[1] = (f32x16)0.0f;
  for (int kti = 0; kti < DD/32; ++kti) {
    int kt = kti*32;
    Frag8 afr[2][3];
    #pragma unroll
    for (int s = 0; s < 2; ++s) {
      float4 af4[2];
      const float* ap = &sT[lm*TP + kt + s*16 + lh*8];
      af4[0] = *reinterpret_cast<const float4*>(ap);
      af4[1] = *reinterpret_cast<const float4*>(ap + 4);
      const float* fv = &af4[0].x;
      #pragma unroll
      for (int j = 0; j < 8; ++j) {
        float x = fv[j];
        unsigned short h1 = f2bf(x);  float r1 = x - bf2f(h1);
        unsigned short h2 = f2bf(r1); float r2 = r1 - bf2f(h2);
        afr[s][0].us[j] = h1; afr[s][1].us[j] = h2; afr[s][2].us[j] = f2bf(r2);
      }
    }
    #pragma unroll
    for (int s = 0; s < 2; ++s)
      #pragma unroll
      for (int ntl = 0; ntl < 2; ++ntl) {
        int ct = wave*2 + ntl;
        size_t boff = ((((size_t)kti*2 + s)*8 + ct)*64 + lane)*8;
        Frag8 b0_, b1_, b2_;
        b0_.v = *reinterpret_cast<const bf16x8*>(Wk + boff);
        b1_.v = *reinterpret_cast<const bf16x8*>(Wk + (size_t)DD*DD + boff);
        b2_.v = *reinterpret_cast<const bf16x8*>(Wk + (size_t)2*DD*DD + boff);
        acc[ntl] = __builtin_amdgcn_mfma_f32_32x32x16_bf16(afr[s][0].v, b0_.v, acc[ntl], 0,0,0);
        acc[ntl] = __builtin_amdgcn_mfma_f32_32x32x16_bf16(afr[s][0].v, b1_.v, acc[ntl], 0,0,0);
        acc[ntl] = __builtin_amdgcn_mfma_f32_32x32x16_bf16(afr[s][1].v, b0_.v, acc[ntl], 0,0,0);
        acc[ntl] = __builtin_amdgcn_mfma_f32_32x32x16_bf16(afr[s][0].v, b2_.v, acc[ntl], 0,0,0);
        acc[ntl] = __builtin_amdgcn_mfma_f32_32x32x16_bf16(afr[s][2].v, b0_.v, acc[ntl], 0,0,0);
        acc[ntl] = __builtin_amdgcn_mfma_f32_32x32x16_bf16(afr[s][1].v, b1_.v, acc[ntl], 0,0,0);
      }
  }

  // epilogue: x2 = lrelu(nv*acc + b) into bufA (bufA free after T phase)
  #pragma unroll
  for (int ntl = 0; ntl < 2; ++ntl) {
    int colbase = wave*64 + ntl*32 + lm;
    float bc = bias[colbase];
    #pragma unroll
    for (int r = 0; r < 16; ++r) {
      int row = (r & 3) + 8*(r >> 2) + 4*lh;
      bufA[row*DD + colbase] = lrelu(snorm[row]*acc[ntl][r] + bc);
    }
  }
  __syncthreads();
  // hs: one wave reproduces original 8-tile + 32-lane butterfly order exactly
  if (wave == 0) {
    float wcol[8];
    #pragma unroll
    for (int nt = 0; nt < 8; ++nt) wcol[nt] = Ws[nt*32 + lm];
    float hsum[16];
    #pragma unroll
    for (int r = 0; r < 16; ++r) {
      int row = (r & 3) + 8*(r >> 2) + 4*lh;
      float hp = 0.f;
      #pragma unroll
      for (int nt = 0; nt < 8; ++nt) hp += bufA[row*DD + nt*32 + lm]*wcol[nt];
      hsum[r] = hp;
    }
    #pragma unroll
    for (int off = 1; off <= 16; off <<= 1)
      #pragma unroll
      for (int r = 0; r < 16; ++r) hsum[r] += __shfl_xor(hsum[r], off);
    if (lm == 0)
      #pragma unroll
      for (int r = 0; r < 16; ++r) {
        int row = (r & 3) + 8*(r >> 2) + 4*lh;
        shs[row] = snorm[row]*hsum[r];
      }
  }
  __syncthreads();
  if (t < n) {
    float s = 0.f;
    for (int m = 0; m < n; ++m) s += sa[m*n + t]*shs[m];   // symmetric
    ssc[t] = snorm[t]*s + bs[0];
  }
  __syncthreads();
  if (t < 64) {
    float sc = (t < n) ? ssc[t] : -INFINITY;
    int si = (t < n) ? t : (1 << 30);
    for (int kk = 0; kk < kp; ++kk) {
      float bs_ = sc; int bi = si;
      for (int off = 32; off; off >>= 1) {
        float os = __shfl_xor(bs_, off);
        int oi = __shfl_xor(bi, off);
        if (os > bs_ || (os == bs_ && oi < bi)) { bs_ = os; bi = oi; }
      }
      if (t == 0) { sidx[kk] = bi; stv[kk] = tanhf(bs_); }
      if (si == bi) sc = -INFINITY;
    }
  }
  __syncthreads();
  float sum = 0.f, mx = -INFINITY;
  #pragma unroll
  for (int j = 0; j < kp; ++j) {
    float v = bufA[sidx[j]*DD + t] * stv[j];
    x_sel_out[((size_t)g*kp + j)*DD + t] = v;
    sum += v; mx = fmaxf(mx, v);
  }
  merged[(size_t)g*1536 + 512 + t] = sum;
  merged[(size_t)g*1536 + 768 + t] = mx;
  { int r = t >> 4, c = t & 15;
    a_out[(size_t)g*kp*kp + t] = sa[sidx[r]*n + sidx[c]]; }
}

// ---------------- layer2 fully fused (LAST): norm + spmm + GEMM + score + topk + readout ----------------
__global__ __launch_bounds__(256, 2) void k_fused2(
    const float* __restrict__ a, const float* __restrict__ xin,
    const unsigned short* __restrict__ Wk, const float* __restrict__ bias,
    const float* __restrict__ Ws, const float* __restrict__ bs,
    float* __restrict__ merged) {
  constexpr int n = KS1;     // 16 nodes in
  constexpr int kp = KS2;    // 8 kept
  constexpr int TP = DD + 4;
  __shared__ float sa[n*n];          // 1 KB
  __shared__ float bufA[n*DD];       // 16 KB
  __shared__ float sT[n*TP];         // 16.6 KB
  __shared__ float snorm[n]; __shared__ float shs[n]; __shared__ float ssc[n];
  __shared__ int sidx[kp]; __shared__ float stv[kp];
  int g = blockIdx.x, t = threadIdx.x;
  int lane = t & 63, wave = t >> 6, lm = lane & 31, lh = lane >> 5;

  for (int e = t; e < n*n; e += 256) sa[e] = a[(size_t)g*n*n + e];
  __syncthreads();
  if (t < n) {
    float dg = 0.f;
    for (int m = 0; m < n; ++m) dg += sa[m*n + t];
    snorm[t] = rsqrtf(fmaxf(dg, 1.f));
  }
  __syncthreads();
  {
    const float4* xp = reinterpret_cast<const float4*>(xin + (size_t)g*n*DD);
    #pragma unroll
    for (int i = 0; i < (n*DD/4)/256; ++i) {
      int e4 = t + i*256;
      float4 v = xp[e4];
      float nv = snorm[e4 >> 6];
      v.x *= nv; v.y *= nv; v.z *= nv; v.w *= nv;
      reinterpret_cast<float4*>(bufA)[e4] = v;
    }
  }
  __syncthreads();
  {
    float acc2[n];
    #pragma unroll
    for (int r = 0; r < n; ++r) acc2[r] = 0.f;
    for (int m = 0; m < n; ++m) {
      float xv = bufA[m*DD + t];
      #pragma unroll
      for (int r = 0; r < n; ++r) acc2[r] += sa[r*n + m]*xv;
    }
    #pragma unroll
    for (int r = 0; r < n; ++r) sT[r*TP + t] = acc2[r];
  }
  __syncthreads();

  f32x16 acc[2];
  acc[0] = (f32x16)0.0f; acc[1] = (f32x16)0.0f;
  for (int kti = 0; kti < DD/32; ++kti) {
    int kt = kti*32;
    Frag8 afr[2][3];
    #pragma unroll
    for (int s = 0; s < 2; ++s) {
      float4 af4[2];
      if (lm < n) {
        const float* ap = &sT[lm*TP + kt + s*16 + lh*8];
        af4[0] = *reinterpret_cast<const float4*>(ap);
        af4[1] = *reinterpret_cast<const float4*>(ap + 4);
      } else {
        af4[0] = make_float4(0.f, 0.f, 0.f, 0.f);
        af4[1] = make_float4(0.f, 0.f, 0.f, 0.f);
      }
      const float* fv = &af4[0].x;
      #pragma unroll
      for (int j = 0; j < 8; ++j) {
        float x = fv[j];
        unsigned short h1 = f2bf(x);  float r1 = x - bf2f(h1);
        unsigned short h2 = f2bf(r1); float r2 = r1 - bf2f(h2);
        afr[s][0].us[j] = h1; afr[s][1].us[j] = h2; afr[s][2].us[j] = f2bf(r2);
      }
    }
    #pragma unroll
    for (int s = 0; s < 2; ++s)
      #pragma unroll
      for (int ntl = 0; ntl < 2; ++ntl) {
        int ct = wave*2 + ntl;
        size_t boff = ((((size_t)kti*2 + s)*8 + ct)*64 + lane)*8;
        Frag8 b0_, b1_, b2_;
        b0_.v = *reinterpret_cast<const bf16x8*>(Wk + boff);
        b1_.v = *reinterpret_cast<const bf16x8*>(Wk + (size_t)DD*DD + boff);
        b2_.v = *reinterpret_cast<const bf16x8*>(Wk + (size_t)2*DD*DD + boff);
        acc[ntl] = __builtin_amdgcn_mfma_f32_32x32x16_bf16(afr[s][0].v, b0_.v, acc[ntl], 0,0,0);
        acc[ntl] = __builtin_amdgcn_mfma_f32_32x32x16_bf16(afr[s][0].v, b1_.v, acc[ntl], 0,0,0);
        acc[ntl] = __builtin_amdgcn_mfma_f32_32x32x16_bf16(afr[s][1].v, b0_.v, acc[ntl], 0,0,0);
        acc[ntl] = __builtin_amdgcn_mfma_f32_32x32x16_bf16(afr[s][0].v, b2_.v, acc[ntl], 0,0,0);
        acc[ntl] = __builtin_amdgcn_mfma_f32_32x32x16_bf16(afr[s][2].v, b0_.v, acc[ntl], 0,0,0);
        acc[ntl] = __builtin_amdgcn_mfma_f32_32x32x16_bf16(afr[s][1].v, b1_.v, acc[ntl], 0,0,0);
      }
  }

  #pragma unroll
  for (int ntl = 0; ntl < 2; ++ntl) {
    int colbase = wave*64 + ntl*32 + lm;
    float bc = bias[colbase];
    #pragma unroll
    for (int r = 0; r < 16; ++r) {
      int row = (r & 3) + 8*(r >> 2) + 4*lh;
      if (row < n) bufA[row*DD + colbase] = lrelu(snorm[row]*acc[ntl][r] + bc);
    }
  }
  __syncthreads();
  if (wave == 0) {
    float wcol[8];
    #pragma unroll
    for (int nt = 0; nt < 8; ++nt) wcol[nt] = Ws[nt*32 + lm];
    float hsum[16];
    #pragma unroll
    for (int r = 0; r < 16; ++r) {
      int row = (r & 3) + 8*(r >> 2) + 4*lh;
      float hp = 0.f;
      if (row < n) {
        #pragma unroll
        for (int nt = 0; nt < 8; ++nt) hp += bufA[row*DD + nt*32 + lm]*wcol[nt];
      }
      hsum[r] = hp;
    }
    #pragma unroll
    for (int off = 1; off <= 16; off <<= 1)
      #pragma unroll
      for (int r = 0; r < 16; ++r) hsum[r] += __shfl_xor(hsum[r], off);
    if (lm == 0)
      #pragma unroll
      for (int r = 0; r < 16; ++r) {
        int row = (r & 3) + 8*(r >> 2) + 4*lh;
        if (row < n) shs[row] = snorm[row]*hsum[r];
      }
  }
  __syncthreads();
  if (t < n) {
    float s = 0.f;
    for (int m = 0; m < n; ++m) s += sa[m*n + t]*shs[m];
    ssc[t] = snorm[t]*s + bs[0];
  }
  __syncthreads();
  if (t < 64) {
    float sc = (t < n) ? ssc[t] : -INFINITY;
    int si = (t < n) ? t : (1 << 30);
    for (int kk = 0; kk < kp; ++kk) {
      float bs_ = sc; int bi = si;
      for (int off = 32; off; off >>= 1) {
        float os = __shfl_xor(bs_, off);
        int oi = __shfl_xor(bi, off);
        if (os > bs_ || (os == bs_ && oi < bi)) { bs_ = os; bi = oi; }
      }
      if (t == 0) { sidx[kk] = bi; stv[kk] = tanhf(bs_); }
      if (si == bi) sc = -INFINITY;
    }
  }
  __syncthreads();
  float sum = 0.f, mx = -INFINITY;
  #pragma unroll
  for (int j = 0; j < kp; ++j) {
    float v = bufA[sidx[j]*DD + t] * stv[j];
    sum += v; mx = fmaxf(mx, v);
  }
  merged[(size_t)g*1536 + 1024 + t] = sum;
  merged[(size_t)g*1536 + 1280 + t] = mx;
}

// ---------------- final MLP: 4 graphs per block for Wd1 reuse ----------------
__global__ void k_mlp(const float* __restrict__ merged, const float* __restrict__ Wd1,
                      const float* __restrict__ bd1, const float* __restrict__ Wd2,
                      const float* __restrict__ bd2, float* __restrict__ out) {
  __shared__ float sm[4*1536];
  __shared__ float sh[4][128];
  int g0 = blockIdx.x*4; int t = threadIdx.x;     // 128 threads
  for (int i = t; i < 4*1536; i += 128) sm[i] = merged[(size_t)g0*1536 + i];
  __syncthreads();
  float a0 = 0.f, a1 = 0.f, a2 = 0.f, a3 = 0.f;
  for (int kk = 0; kk < 1536; ++kk) {
    float w = Wd1[(size_t)kk*128 + t];
    a0 += sm[kk]*w; a1 += sm[1536 + kk]*w; a2 += sm[3072 + kk]*w; a3 += sm[4608 + kk]*w;
  }
  float b = bd1[t];
  sh[0][t] = lrelu(a0 + b); sh[1][t] = lrelu(a1 + b);
  sh[2][t] = lrelu(a2 + b); sh[3][t] = lrelu(a3 + b);
  __syncthreads();
  if (t < 8) {
    int gi = t >> 1, c = t & 1;
    float o = 0.f;
    for (int kk = 0; kk < 128; ++kk) o += sh[gi][kk]*Wd2[kk*2 + c];
    out[(size_t)(g0 + gi)*2 + c] = 1.f/(1.f + expf(-(o + bd2[c])));
  }
}

extern "C" void kernel_launch(void* const* d_in, const int* in_sizes, int n_in,
                              void* d_out, int out_size, void* d_ws, size_t ws_size,
                              hipStream_t stream) {
  const float* feat = (const float*)d_in[0];
  const float* adj  = (const float*)d_in[1];
  const float* W0 = (const float*)d_in[2];  const float* b0  = (const float*)d_in[3];
  const float* Ws0= (const float*)d_in[4];  const float* bs0 = (const float*)d_in[5];
  const float* W1 = (const float*)d_in[6];  const float* b1  = (const float*)d_in[7];
  const float* Ws1= (const float*)d_in[8];  const float* bs1 = (const float*)d_in[9];
  const float* W2 = (const float*)d_in[10]; const float* b2  = (const float*)d_in[11];
  const float* Ws2= (const float*)d_in[12]; const float* bs2 = (const float*)d_in[13];
  const float* Wd1= (const float*)d_in[14]; const float* bd1 = (const float*)d_in[15];
  const float* Wd2= (const float*)d_in[16]; const float* bd2 = (const float*)d_in[17];
  float* out = (float*)d_out;

  char* ws = (char*)d_ws;
  size_t off = 0;
  auto alloc = [&](size_t bytes) -> char* {
    char* p = ws + off; off += (bytes + 255) & ~(size_t)255; return p;
  };
  float* norm0 = (float*)alloc((size_t)GG*NN*4);
  unsigned long long* mask0 = (unsigned long long*)alloc((size_t)GG*NN*4*8);
  float* hs0   = (float*)alloc((size_t)GG*NN*4);
  float* merged= (float*)alloc((size_t)GG*1536*4);
  unsigned short* W0s = (unsigned short*)alloc((size_t)3*FF*DD*2);
  unsigned short* W1s = (unsigned short*)alloc((size_t)3*DD*DD*2);
  unsigned short* W2s = (unsigned short*)alloc((size_t)3*DD*DD*2);
  float* T0     = (float*)alloc((size_t)GG*NN*FF*4);        // 134 MB
  float* x_sel1 = (float*)alloc((size_t)GG*KS0*DD*4);       //  32 MB
  float* a1     = (float*)alloc((size_t)GG*KS0*KS0*4);      //   4 MB
  float* x_sel2 = (float*)alloc((size_t)GG*KS1*DD*4);       //  16 MB
  float* a2     = (float*)alloc((size_t)GG*KS1*KS1*4);      //   1 MB

  // ---- weight pre-split (one launch for all three) ----
  k_splitW_all<<<(FF*DD + 2*DD*DD)/256, 256, 0, stream>>>(W0, W1, W2, W0s, W1s, W2s);

  // ---- layer 0 ----
  k_maskrow<<<GG*NN/4, 256, 0, stream>>>(adj, norm0, mask0);
  k_spmm_s<<<4*GG, 256, 0, stream>>>(feat, mask0, norm0, T0);
  k_gemm0<<<GG*NN/128, 256, 0, stream>>>(T0, W0s, norm0, b0, Ws0, hs0);
  k_topk_sel0<<<GG, 256, 0, stream>>>(mask0, hs0, norm0, bs0, T0, W0, b0, x_sel1, a1, merged);

  // ---- layer 1 (fully fused per graph) ----
  k_fused1<<<GG, 256, 0, stream>>>(a1, x_sel1, W1s, b1, Ws1, bs1, x_sel2, a2, merged);

  // ---- layer 2 (fully fused per graph, LAST) ----
  k_fused2<<<GG, 256, 0, stream>>>(a2, x_sel2, W2s, b2, Ws2, bs2, merged);

  // ---- MLP head ----
  k_mlp<<<GG/4, 128, 0, stream>>>(merged, Wd1, bd1, Wd2, bd2, out);

  (void)in_sizes; (void)n_in; (void)out_size; (void)ws_size;
}

// Round 10
// 909.180 us; speedup vs baseline: 1.0219x; 1.0219x over previous
//
#include <hip/hip_runtime.h>
#include <math.h>

constexpr int GG  = 1024;   // graphs
constexpr int NN  = 256;    // nodes layer0
constexpr int FF  = 128;    // input feat
constexpr int DD  = 256;    // hidden
constexpr int KS0 = 32, KS1 = 16, KS2 = 8;

__device__ __forceinline__ float lrelu(float x){ return x >= 0.f ? x : 0.01f*x; }

// bf16 helpers
__device__ __forceinline__ unsigned short f2bf(float f) {
  unsigned u = __float_as_uint(f);
  unsigned r = (u + 0x7FFFu + ((u >> 16) & 1u)) >> 16;
  return (unsigned short)r;
}
__device__ __forceinline__ float bf2f(unsigned short h) {
  return __uint_as_float(((unsigned)h) << 16);
}

typedef __attribute__((ext_vector_type(8)))  __bf16 bf16x8;
typedef __attribute__((ext_vector_type(16))) float  f32x16;

union Frag8 { unsigned short us[8]; unsigned long long u64[2]; bf16x8 v; };

typedef __attribute__((address_space(1))) void gvoid;
typedef __attribute__((address_space(3))) void lvoid;
__device__ __forceinline__ void async_cp16(const unsigned short* g, unsigned short* l) {
  __builtin_amdgcn_global_load_lds((const gvoid*)g, (lvoid*)l, 16, 0, 0);
}

// ---------------- pre-split all 3 weights into 3 bf16 planes, frag-blocked kti-major ----------------
__global__ void k_splitW_all(const float* __restrict__ Wa, const float* __restrict__ Wb,
                             const float* __restrict__ Wc,
                             unsigned short* __restrict__ oa, unsigned short* __restrict__ ob,
                             unsigned short* __restrict__ oc) {
  int e = blockIdx.x*256 + threadIdx.x;
  if (e >= FF*DD + 2*DD*DD) return;
  const float* W; unsigned short* out; int K;
  if (e < FF*DD)                { W = Wa; out = oa; K = FF; }
  else if (e < FF*DD + DD*DD)   { e -= FF*DD; W = Wb; out = ob; K = DD; }
  else                          { e -= FF*DD + DD*DD; W = Wc; out = oc; K = DD; }
  int j    = e & 7;
  int lane = (e >> 3) & 63;
  int nt   = (e >> 9) & 7;
  int s    = (e >> 12) & 1;
  int kti  = e >> 13;
  int n = nt*32 + (lane & 31);
  int k = kti*32 + s*16 + ((lane >> 5) << 3) + j;
  float x = W[(size_t)k*DD + n];
  unsigned short h1 = f2bf(x);  float r1 = x - bf2f(h1);
  unsigned short h2 = f2bf(r1); float r2 = r1 - bf2f(h2);
  unsigned short h3 = f2bf(r2);
  out[e] = h1; out[DD*K + e] = h2; out[2*DD*K + e] = h3;
}

// ---------------- mask + norm: wave per row; 4 x ballot -> 256-bit row mask ----------------
__global__ void k_maskrow(const float* __restrict__ adj, float* __restrict__ norm0,
                          unsigned long long* __restrict__ mask) {
  int row = blockIdx.x*4 + (threadIdx.x >> 6);
  int lane = threadIdx.x & 63;
  const float* ar = adj + (size_t)row*NN;
  float f0 = ar[lane], f1 = ar[64 + lane], f2 = ar[128 + lane], f3 = ar[192 + lane];
  unsigned long long m0 = __ballot(f0 > 0.5f);
  unsigned long long m1 = __ballot(f1 > 0.5f);
  unsigned long long m2 = __ballot(f2 > 0.5f);
  unsigned long long m3 = __ballot(f3 > 0.5f);
  if (lane < 4) {
    unsigned long long mm = lane == 0 ? m0 : lane == 1 ? m1 : lane == 2 ? m2 : m3;
    mask[(size_t)row*4 + lane] = mm;
  }
  if (lane == 0) {
    int cnt = __popcll(m0) + __popcll(m1) + __popcll(m2) + __popcll(m3);
    norm0[row] = rsqrtf(fmaxf((float)cnt, 1.0f));
  }
}

// ---------------- sparse spmm: one thread per row, 32-col quarters (champion config) ----------------
__global__ __launch_bounds__(256, 4) void k_spmm_s(
    const float* __restrict__ feat, const unsigned long long* __restrict__ mask,
    const float* __restrict__ norm0, float* __restrict__ T0) {
  constexpr int ST = 36;                  // floats; rows 144 B, 16B-aligned
  __shared__ float ls[NN*ST];             // 36864 B
  __shared__ float snorm[NN];
  int bid = blockIdx.x;
  int g = bid >> 2, q = bid & 3;
  int t = threadIdx.x;
  const float* Xg = feat + (size_t)g*NN*FF + q*32;

  snorm[t] = norm0[g*NN + t];
  const unsigned long long* mp = mask + ((size_t)g*NN + t)*4;
  unsigned long long mrow[4];
  #pragma unroll
  for (int w = 0; w < 4; ++w) mrow[w] = mp[w];
  __syncthreads();

  // stage 256 rows x 32 cols of X*norm into LDS (8 lanes/row -> 128 B contiguous per row)
  #pragma unroll
  for (int i = 0; i < 8; ++i) {
    int e = t + i*256;
    int r = e >> 3, c4 = (e & 7)*4;
    float4 v = *reinterpret_cast<const float4*>(Xg + (size_t)r*FF + c4);
    float nv = snorm[r];
    v.x *= nv; v.y *= nv; v.z *= nv; v.w *= nv;
    *reinterpret_cast<float4*>(&ls[r*ST + c4]) = v;
  }
  __syncthreads();

  // thread t owns output row t: sum neighbor rows in ascending index (matches dense einsum order)
  float4 acc[8];
  #pragma unroll
  for (int i = 0; i < 8; ++i) acc[i] = make_float4(0.f, 0.f, 0.f, 0.f);
  #pragma unroll
  for (int w = 0; w < 4; ++w) {
    unsigned long long m = mrow[w];
    while (m) {
      int c = __builtin_ctzll(m);
      const float4* xp = reinterpret_cast<const float4*>(&ls[(w*64 + c)*ST]);
      #pragma unroll
      for (int i = 0; i < 8; ++i) {
        float4 v = xp[i];
        acc[i].x += v.x; acc[i].y += v.y; acc[i].z += v.z; acc[i].w += v.w;
      }
      m &= m - 1;
    }
  }
  float* op = T0 + ((size_t)g*NN + t)*FF + q*32;
  #pragma unroll
  for (int i = 0; i < 8; ++i)
    *reinterpret_cast<float4*>(op + i*4) = acc[i];
}

// ---------------- layer0 GEMM: 4-wave blocks, B staged via global_load_lds ----------------
__global__ __launch_bounds__(256, 2) void k_gemm0(
    const float* __restrict__ Tmat, const unsigned short* __restrict__ Wk,
    const float* __restrict__ normv, const float* __restrict__ bias,
    const float* __restrict__ Ws, float* __restrict__ hs) {
  __shared__ unsigned short bsh[3*8192];   // 48 KB: one k-tile of all 3 planes
  int t = threadIdx.x;
  int lane = t & 63, wave = t >> 6;
  int lm = lane & 31, lh = lane >> 5;
  int rowbase = blockIdx.x*128 + wave*32;

  f32x16 acc[8];
  #pragma unroll
  for (int nt = 0; nt < 8; ++nt) acc[nt] = (f32x16)0.0f;

  for (int kti = 0; kti < 4; ++kti) {
    int kt = kti*32;
    float4 af[2][2];
    #pragma unroll
    for (int s = 0; s < 2; ++s) {
      const float* ap = Tmat + (size_t)(rowbase + lm)*FF + kt + s*16 + lh*8;
      af[s][0] = *reinterpret_cast<const float4*>(ap);
      af[s][1] = *reinterpret_cast<const float4*>(ap + 4);
    }
    __syncthreads();
    #pragma unroll
    for (int sp = 0; sp < 3; ++sp)
      #pragma unroll
      for (int r = 0; r < 4; ++r) {
        const unsigned short* src = Wk + (size_t)sp*DD*FF + (size_t)kti*8192 + r*2048 + t*8;
        unsigned short* dst = bsh + sp*8192 + r*2048 + t*8;
        async_cp16(src, dst);
      }
    __syncthreads();
    Frag8 afr[2][3];
    #pragma unroll
    for (int s = 0; s < 2; ++s) {
      const float* fv = &af[s][0].x;
      #pragma unroll
      for (int j = 0; j < 8; ++j) {
        float x = fv[j];
        unsigned short h1 = f2bf(x);  float r1 = x - bf2f(h1);
        unsigned short h2 = f2bf(r1); float r2 = r1 - bf2f(h2);
        afr[s][0].us[j] = h1; afr[s][1].us[j] = h2; afr[s][2].us[j] = f2bf(r2);
      }
    }
    #pragma unroll
    for (int s = 0; s < 2; ++s)
      #pragma unroll
      for (int nt = 0; nt < 8; ++nt) {
        const unsigned short* bp = bsh + ((s*8 + nt)*64 + lane)*8;
        Frag8 b0_, b1_, b2_;
        b0_.v = *reinterpret_cast<const bf16x8*>(bp);
        b1_.v = *reinterpret_cast<const bf16x8*>(bp + 8192);
        b2_.v = *reinterpret_cast<const bf16x8*>(bp + 16384);
        acc[nt] = __builtin_amdgcn_mfma_f32_32x32x16_bf16(afr[s][0].v, b0_.v, acc[nt], 0,0,0);
        acc[nt] = __builtin_amdgcn_mfma_f32_32x32x16_bf16(afr[s][0].v, b1_.v, acc[nt], 0,0,0);
        acc[nt] = __builtin_amdgcn_mfma_f32_32x32x16_bf16(afr[s][1].v, b0_.v, acc[nt], 0,0,0);
        acc[nt] = __builtin_amdgcn_mfma_f32_32x32x16_bf16(afr[s][0].v, b2_.v, acc[nt], 0,0,0);
        acc[nt] = __builtin_amdgcn_mfma_f32_32x32x16_bf16(afr[s][2].v, b0_.v, acc[nt], 0,0,0);
        acc[nt] = __builtin_amdgcn_mfma_f32_32x32x16_bf16(afr[s][1].v, b1_.v, acc[nt], 0,0,0);
      }
  }

  float bcol[8], wcol[8];
  #pragma unroll
  for (int nt = 0; nt < 8; ++nt) { int col = nt*32 + lm; bcol[nt] = bias[col]; wcol[nt] = Ws[col]; }
  float hsum[16];
  #pragma unroll
  for (int r = 0; r < 16; ++r) {
    int row = rowbase + (r & 3) + 8*(r >> 2) + 4*lh;
    float nv = normv[row];
    float hp = 0.f;
    #pragma unroll
    for (int nt = 0; nt < 8; ++nt) hp += lrelu(nv*acc[nt][r] + bcol[nt])*wcol[nt];
    hsum[r] = hp;
  }
  #pragma unroll
  for (int off = 1; off <= 16; off <<= 1)
    #pragma unroll
    for (int r = 0; r < 16; ++r) hsum[r] += __shfl_xor(hsum[r], off);
  if (lm == 0)
    #pragma unroll
    for (int r = 0; r < 16; ++r) {
      int row = rowbase + (r & 3) + 8*(r >> 2) + 4*lh;
      hs[row] = normv[row]*hsum[r];
    }
}

// ---------------- layer0: score + top-k + selection fused (per graph) ----------------
__global__ __launch_bounds__(256) void k_topk_sel0(
    const unsigned long long* __restrict__ mask, const float* __restrict__ hs,
    const float* __restrict__ norm0, const float* __restrict__ bs,
    const float* __restrict__ T0, const float* __restrict__ W0,
    const float* __restrict__ b0, float* __restrict__ x_sel,
    float* __restrict__ a1, float* __restrict__ merged) {
  __shared__ float sh[NN];
  __shared__ float ssc[NN];
  __shared__ float sT[KS0*FF];     // 16 KB
  __shared__ int sidx[KS0]; __shared__ float stv[KS0]; __shared__ float snv[KS0];
  int g = blockIdx.x, t = threadIdx.x;

  sh[t] = hs[g*NN + t];
  __syncthreads();
  const unsigned long long* mr = mask + ((size_t)g*NN + t)*4;
  float s = 0.f;
  #pragma unroll
  for (int w = 0; w < 4; ++w) {
    unsigned long long m = mr[w];
    const float* base = sh + w*64;
    while (m) {
      int c = __builtin_ctzll(m);
      s += base[c];
      m &= m - 1;
    }
  }
  ssc[t] = norm0[g*NN + t]*s + bs[0];
  __syncthreads();
  if (t < 64) {
    float sv[4]; int si[4];
    #pragma unroll
    for (int e = 0; e < 4; ++e) { sv[e] = ssc[e*64 + t]; si[e] = e*64 + t; }
    for (int kk = 0; kk < KS0; ++kk) {
      float bs_ = -INFINITY; int bi = 1 << 30;
      #pragma unroll
      for (int e = 0; e < 4; ++e)
        if (sv[e] > bs_ || (sv[e] == bs_ && si[e] < bi)) { bs_ = sv[e]; bi = si[e]; }
      for (int off = 32; off; off >>= 1) {
        float os = __shfl_xor(bs_, off);
        int oi = __shfl_xor(bi, off);
        if (os > bs_ || (os == bs_ && oi < bi)) { bs_ = os; bi = oi; }
      }
      if (t == 0) { sidx[kk] = bi; stv[kk] = tanhf(bs_); }
      #pragma unroll
      for (int e = 0; e < 4; ++e) if (si[e] == bi) sv[e] = -INFINITY;
    }
  }
  __syncthreads();
  // selection: recompute x1 rows for top-32, gate, readout, a1 from mask
  if (t < KS0) snv[t] = norm0[g*NN + sidx[t]];
  #pragma unroll
  for (int i = 0; i < 4; ++i) {
    int e4 = t + i*256;
    int r = e4 >> 5, c4 = e4 & 31;
    reinterpret_cast<float4*>(sT)[e4] =
        *reinterpret_cast<const float4*>(&T0[((size_t)g*NN + sidx[r])*FF + c4*4]);
  }
  __syncthreads();
  float sum[KS0];
  #pragma unroll
  for (int j = 0; j < KS0; ++j) sum[j] = 0.f;
  for (int k = 0; k < FF; k += 4) {
    float4 w;
    w.x = W0[(size_t)(k+0)*DD + t]; w.y = W0[(size_t)(k+1)*DD + t];
    w.z = W0[(size_t)(k+2)*DD + t]; w.w = W0[(size_t)(k+3)*DD + t];
    #pragma unroll
    for (int j = 0; j < KS0; ++j) {
      float4 tv4 = *reinterpret_cast<const float4*>(&sT[j*FF + k]);
      sum[j] += tv4.x*w.x + tv4.y*w.y + tv4.z*w.z + tv4.w*w.w;
    }
  }
  float b = b0[t];
  float ssum = 0.f, mx = -INFINITY;
  #pragma unroll
  for (int j = 0; j < KS0; ++j) {
    float val = lrelu(snv[j]*sum[j] + b) * stv[j];
    x_sel[((size_t)g*KS0 + j)*DD + t] = val;
    ssum += val; mx = fmaxf(mx, val);
  }
  merged[(size_t)g*1536 + t] = ssum;
  merged[(size_t)g*1536 + 256 + t] = mx;
  for (int e = t; e < KS0*KS0; e += 256) {
    int r = e >> 5, c = e & 31;
    int nr = sidx[r], nc = sidx[c];
    unsigned long long m = mask[((size_t)g*NN + nr)*4 + (nc >> 6)];
    a1[(size_t)g*KS0*KS0 + e] = (float)((m >> (nc & 63)) & 1ull);
  }
}

// ---------------- layer1 fully fused: norm + spmm + GEMM + score + topk + pool (per graph) ----------------
__global__ __launch_bounds__(256, 2) void k_fused1(
    const float* __restrict__ a, const float* __restrict__ xin,
    const unsigned short* __restrict__ Wk, const float* __restrict__ bias,
    const float* __restrict__ Ws, const float* __restrict__ bs,
    float* __restrict__ x_sel_out, float* __restrict__ a_out,
    float* __restrict__ merged) {
  constexpr int n = KS0;     // 32 nodes in
  constexpr int kp = KS1;    // 16 kept
  constexpr int TP = DD + 4; // padded LDS k-stride for T (260 floats, 16B-aligned rows)
  __shared__ float sa[n*n];          // 4 KB
  __shared__ float bufA[n*DD];       // 32 KB: x*norm, then x2
  __shared__ float sT[n*TP];         // 32.5 KB
  __shared__ float snorm[n]; __shared__ float shs[n]; __shared__ float ssc[n];
  __shared__ int sidx[kp]; __shared__ float stv[kp];
  int g = blockIdx.x, t = threadIdx.x;
  int lane = t & 63, wave = t >> 6, lm = lane & 31, lh = lane >> 5;

  for (int e = t; e < n*n; e += 256) sa[e] = a[(size_t)g*n*n + e];
  __syncthreads();
  if (t < n) {
    float dg = 0.f;
    for (int m = 0; m < n; ++m) dg += sa[m*n + t];   // a symmetric: == sa[t*n+m]
    snorm[t] = rsqrtf(fmaxf(dg, 1.f));
  }
  __syncthreads();
  {
    const float4* xp = reinterpret_cast<const float4*>(xin + (size_t)g*n*DD);
    #pragma unroll
    for (int i = 0; i < (n*DD/4)/256; ++i) {
      int e4 = t + i*256;
      float4 v = xp[e4];
      float nv = snorm[e4 >> 6];
      v.x *= nv; v.y *= nv; v.z *= nv; v.w *= nv;
      reinterpret_cast<float4*>(bufA)[e4] = v;
    }
  }
  __syncthreads();
  { // T = sa @ bufA ; thread t owns column t
    float acc2[n];
    #pragma unroll
    for (int r = 0; r < n; ++r) acc2[r] = 0.f;
    for (int m = 0; m < n; ++m) {
      float xv = bufA[m*DD + t];
      #pragma unroll
      for (int r = 0; r < n; ++r) acc2[r] += sa[r*n + m]*xv;
    }
    #pragma unroll
    for (int r = 0; r < n; ++r) sT[r*TP + t] = acc2[r];
  }
  __syncthreads();

  // GEMM: wave handles 64 cols (2 col-tiles); rows = all 32
  f32x16 acc[2];
  acc[0] = (f32x16)0.0f; acc[1] = (f32x16)0.0f;
  for (int kti = 0; kti < DD/32; ++kti) {
    int kt = kti*32;
    Frag8 afr[2][3];
    #pragma unroll
    for (int s = 0; s < 2; ++s) {
      float4 af4[2];
      const float* ap = &sT[lm*TP + kt + s*16 + lh*8];
      af4[0] = *reinterpret_cast<const float4*>(ap);
      af4[1] = *reinterpret_cast<const float4*>(ap + 4);
      const float* fv = &af4[0].x;
      #pragma unroll
      for (int j = 0; j < 8; ++j) {
        float x = fv[j];
        unsigned short h1 = f2bf(x);  float r1 = x - bf2f(h1);
        unsigned short h2 = f2bf(r1); float r2 = r1 - bf2f(h2);
        afr[s][0].us[j] = h1; afr[s][1].us[j] = h2; afr[s][2].us[j] = f2bf(r2);
      }
    }
    #pragma unroll
    for (int s = 0; s < 2; ++s)
      #pragma unroll
      for (int ntl = 0; ntl < 2; ++ntl) {
        int ct = wave*2 + ntl;
        size_t boff = ((((size_t)kti*2 + s)*8 + ct)*64 + lane)*8;
        Frag8 b0_, b1_, b2_;
        b0_.v = *reinterpret_cast<const bf16x8*>(Wk + boff);
        b1_.v = *reinterpret_cast<const bf16x8*>(Wk + (size_t)DD*DD + boff);
        b2_.v = *reinterpret_cast<const bf16x8*>(Wk + (size_t)2*DD*DD + boff);
        acc[ntl] = __builtin_amdgcn_mfma_f32_32x32x16_bf16(afr[s][0].v, b0_.v, acc[ntl], 0,0,0);
        acc[ntl] = __builtin_amdgcn_mfma_f32_32x32x16_bf16(afr[s][0].v, b1_.v, acc[ntl], 0,0,0);
        acc[ntl] = __builtin_amdgcn_mfma_f32_32x32x16_bf16(afr[s][1].v, b0_.v, acc[ntl], 0,0,0);
        acc[ntl] = __builtin_amdgcn_mfma_f32_32x32x16_bf16(afr[s][0].v, b2_.v, acc[ntl], 0,0,0);
        acc[ntl] = __builtin_amdgcn_mfma_f32_32x32x16_bf16(afr[s][2].v, b0_.v, acc[ntl], 0,0,0);
        acc[ntl] = __builtin_amdgcn_mfma_f32_32x32x16_bf16(afr[s][1].v, b1_.v, acc[ntl], 0,0,0);
      }
  }

  // epilogue: x2 = lrelu(nv*acc + b) into bufA (bufA free after T phase)
  #pragma unroll
  for (int ntl = 0; ntl < 2; ++ntl) {
    int colbase = wave*64 + ntl*32 + lm;
    float bc = bias[colbase];
    #pragma unroll
    for (int r = 0; r < 16; ++r) {
      int row = (r & 3) + 8*(r >> 2) + 4*lh;
      bufA[row*DD + colbase] = lrelu(snorm[row]*acc[ntl][r] + bc);
    }
  }
  __syncthreads();
  // hs: one wave reproduces original 8-tile + 32-lane butterfly order exactly
  if (wave == 0) {
    float wcol[8];
    #pragma unroll
    for (int nt = 0; nt < 8; ++nt) wcol[nt] = Ws[nt*32 + lm];
    float hsum[16];
    #pragma unroll
    for (int r = 0; r < 16; ++r) {
      int row = (r & 3) + 8*(r >> 2) + 4*lh;
      float hp = 0.f;
      #pragma unroll
      for (int nt = 0; nt < 8; ++nt) hp += bufA[row*DD + nt*32 + lm]*wcol[nt];
      hsum[r] = hp;
    }
    #pragma unroll
    for (int off = 1; off <= 16; off <<= 1)
      #pragma unroll
      for (int r = 0; r < 16; ++r) hsum[r] += __shfl_xor(hsum[r], off);
    if (lm == 0)
      #pragma unroll
      for (int r = 0; r < 16; ++r) {
        int row = (r & 3) + 8*(r >> 2) + 4*lh;
        shs[row] = snorm[row]*hsum[r];
      }
  }
  __syncthreads();
  if (t < n) {
    float s = 0.f;
    for (int m = 0; m < n; ++m) s += sa[m*n + t]*shs[m];   // symmetric
    ssc[t] = snorm[t]*s + bs[0];
  }
  __syncthreads();
  if (t < 64) {
    float sc = (t < n) ? ssc[t] : -INFINITY;
    int si = (t < n) ? t : (1 << 30);
    for (int kk = 0; kk < kp; ++kk) {
      float bs_ = sc; int bi = si;
      for (int off = 32; off; off >>= 1) {
        float os = __shfl_xor(bs_, off);
        int oi = __shfl_xor(bi, off);
        if (os > bs_ || (os == bs_ && oi < bi)) { bs_ = os; bi = oi; }
      }
      if (t == 0) { sidx[kk] = bi; stv[kk] = tanhf(bs_); }
      if (si == bi) sc = -INFINITY;
    }
  }
  __syncthreads();
  float sum = 0.f, mx = -INFINITY;
  #pragma unroll
  for (int j = 0; j < kp; ++j) {
    float v = bufA[sidx[j]*DD + t] * stv[j];
    x_sel_out[((size_t)g*kp + j)*DD + t] = v;
    sum += v; mx = fmaxf(mx, v);
  }
  merged[(size_t)g*1536 + 512 + t] = sum;
  merged[(size_t)g*1536 + 768 + t] = mx;
  { int r = t >> 4, c = t & 15;
    a_out[(size_t)g*kp*kp + t] = sa[sidx[r]*n + sidx[c]]; }
}

// ---------------- layer2 fully fused (LAST): norm + spmm + GEMM + score + topk + readout ----------------
__global__ __launch_bounds__(256, 2) void k_fused2(
    const float* __restrict__ a, const float* __restrict__ xin,
    const unsigned short* __restrict__ Wk, const float* __restrict__ bias,
    const float* __restrict__ Ws, const float* __restrict__ bs,
    float* __restrict__ merged) {
  constexpr int n = KS1;     // 16 nodes in
  constexpr int kp = KS2;    // 8 kept
  constexpr int TP = DD + 4;
  __shared__ float sa[n*n];          // 1 KB
  __shared__ float bufA[n*DD];       // 16 KB
  __shared__ float sT[n*TP];         // 16.6 KB
  __shared__ float snorm[n]; __shared__ float shs[n]; __shared__ float ssc[n];
  __shared__ int sidx[kp]; __shared__ float stv[kp];
  int g = blockIdx.x, t = threadIdx.x;
  int lane = t & 63, wave = t >> 6, lm = lane & 31, lh = lane >> 5;

  for (int e = t; e < n*n; e += 256) sa[e] = a[(size_t)g*n*n + e];
  __syncthreads();
  if (t < n) {
    float dg = 0.f;
    for (int m = 0; m < n; ++m) dg += sa[m*n + t];
    snorm[t] = rsqrtf(fmaxf(dg, 1.f));
  }
  __syncthreads();
  {
    const float4* xp = reinterpret_cast<const float4*>(xin + (size_t)g*n*DD);
    #pragma unroll
    for (int i = 0; i < (n*DD/4)/256; ++i) {
      int e4 = t + i*256;
      float4 v = xp[e4];
      float nv = snorm[e4 >> 6];
      v.x *= nv; v.y *= nv; v.z *= nv; v.w *= nv;
      reinterpret_cast<float4*>(bufA)[e4] = v;
    }
  }
  __syncthreads();
  {
    float acc2[n];
    #pragma unroll
    for (int r = 0; r < n; ++r) acc2[r] = 0.f;
    for (int m = 0; m < n; ++m) {
      float xv = bufA[m*DD + t];
      #pragma unroll
      for (int r = 0; r < n; ++r) acc2[r] += sa[r*n + m]*xv;
    }
    #pragma unroll
    for (int r = 0; r < n; ++r) sT[r*TP + t] = acc2[r];
  }
  __syncthreads();

  f32x16 acc[2];
  acc[0] = (f32x16)0.0f; acc[1] = (f32x16)0.0f;
  for (int kti = 0; kti < DD/32; ++kti) {
    int kt = kti*32;
    Frag8 afr[2][3];
    #pragma unroll
    for (int s = 0; s < 2; ++s) {
      float4 af4[2];
      if (lm < n) {
        const float* ap = &sT[lm*TP + kt + s*16 + lh*8];
        af4[0] = *reinterpret_cast<const float4*>(ap);
        af4[1] = *reinterpret_cast<const float4*>(ap + 4);
      } else {
        af4[0] = make_float4(0.f, 0.f, 0.f, 0.f);
        af4[1] = make_float4(0.f, 0.f, 0.f, 0.f);
      }
      const float* fv = &af4[0].x;
      #pragma unroll
      for (int j = 0; j < 8; ++j) {
        float x = fv[j];
        unsigned short h1 = f2bf(x);  float r1 = x - bf2f(h1);
        unsigned short h2 = f2bf(r1); float r2 = r1 - bf2f(h2);
        afr[s][0].us[j] = h1; afr[s][1].us[j] = h2; afr[s][2].us[j] = f2bf(r2);
      }
    }
    #pragma unroll
    for (int s = 0; s < 2; ++s)
      #pragma unroll
      for (int ntl = 0; ntl < 2; ++ntl) {
        int ct = wave*2 + ntl;
        size_t boff = ((((size_t)kti*2 + s)*8 + ct)*64 + lane)*8;
        Frag8 b0_, b1_, b2_;
        b0_.v = *reinterpret_cast<const bf16x8*>(Wk + boff);
        b1_.v = *reinterpret_cast<const bf16x8*>(Wk + (size_t)DD*DD + boff);
        b2_.v = *reinterpret_cast<const bf16x8*>(Wk + (size_t)2*DD*DD + boff);
        acc[ntl] = __builtin_amdgcn_mfma_f32_32x32x16_bf16(afr[s][0].v, b0_.v, acc[ntl], 0,0,0);
        acc[ntl] = __builtin_amdgcn_mfma_f32_32x32x16_bf16(afr[s][0].v, b1_.v, acc[ntl], 0,0,0);
        acc[ntl] = __builtin_amdgcn_mfma_f32_32x32x16_bf16(afr[s][1].v, b0_.v, acc[ntl], 0,0,0);
        acc[ntl] = __builtin_amdgcn_mfma_f32_32x32x16_bf16(afr[s][0].v, b2_.v, acc[ntl], 0,0,0);
        acc[ntl] = __builtin_amdgcn_mfma_f32_32x32x16_bf16(afr[s][2].v, b0_.v, acc[ntl], 0,0,0);
        acc[ntl] = __builtin_amdgcn_mfma_f32_32x32x16_bf16(afr[s][1].v, b1_.v, acc[ntl], 0,0,0);
      }
  }

  #pragma unroll
  for (int ntl = 0; ntl < 2; ++ntl) {
    int colbase = wave*64 + ntl*32 + lm;
    float bc = bias[colbase];
    #pragma unroll
    for (int r = 0; r < 16; ++r) {
      int row = (r & 3) + 8*(r >> 2) + 4*lh;
      if (row < n) bufA[row*DD + colbase] = lrelu(snorm[row]*acc[ntl][r] + bc);
    }
  }
  __syncthreads();
  if (wave == 0) {
    float wcol[8];
    #pragma unroll
    for (int nt = 0; nt < 8; ++nt) wcol[nt] = Ws[nt*32 + lm];
    float hsum[16];
    #pragma unroll
    for (int r = 0; r < 16; ++r) {
      int row = (r & 3) + 8*(r >> 2) + 4*lh;
      float hp = 0.f;
      if (row < n) {
        #pragma unroll
        for (int nt = 0; nt < 8; ++nt) hp += bufA[row*DD + nt*32 + lm]*wcol[nt];
      }
      hsum[r] = hp;
    }
    #pragma unroll
    for (int off = 1; off <= 16; off <<= 1)
      #pragma unroll
      for (int r = 0; r < 16; ++r) hsum[r] += __shfl_xor(hsum[r], off);
    if (lm == 0)
      #pragma unroll
      for (int r = 0; r < 16; ++r) {
        int row = (r & 3) + 8*(r >> 2) + 4*lh;
        if (row < n) shs[row] = snorm[row]*hsum[r];
      }
  }
  __syncthreads();
  if (t < n) {
    float s = 0.f;
    for (int m = 0; m < n; ++m) s += sa[m*n + t]*shs[m];
    ssc[t] = snorm[t]*s + bs[0];
  }
  __syncthreads();
  if (t < 64) {
    float sc = (t < n) ? ssc[t] : -INFINITY;
    int si = (t < n) ? t : (1 << 30);
    for (int kk = 0; kk < kp; ++kk) {
      float bs_ = sc; int bi = si;
      for (int off = 32; off; off >>= 1) {
        float os = __shfl_xor(bs_, off);
        int oi = __shfl_xor(bi, off);
        if (os > bs_ || (os == bs_ && oi < bi)) { bs_ = os; bi = oi; }
      }
      if (t == 0) { sidx[kk] = bi; stv[kk] = tanhf(bs_); }
      if (si == bi) sc = -INFINITY;
    }
  }
  __syncthreads();
  float sum = 0.f, mx = -INFINITY;
  #pragma unroll
  for (int j = 0; j < kp; ++j) {
    float v = bufA[sidx[j]*DD + t] * stv[j];
    sum += v; mx = fmaxf(mx, v);
  }
  merged[(size_t)g*1536 + 1024 + t] = sum;
  merged[(size_t)g*1536 + 1280 + t] = mx;
}

// ---------------- final MLP: 4 graphs per block for Wd1 reuse ----------------
__global__ void k_mlp(const float* __restrict__ merged, const float* __restrict__ Wd1,
                      const float* __restrict__ bd1, const float* __restrict__ Wd2,
                      const float* __restrict__ bd2, float* __restrict__ out) {
  __shared__ float sm[4*1536];
  __shared__ float sh[4][128];
  int g0 = blockIdx.x*4; int t = threadIdx.x;     // 128 threads
  for (int i = t; i < 4*1536; i += 128) sm[i] = merged[(size_t)g0*1536 + i];
  __syncthreads();
  float a0 = 0.f, a1 = 0.f, a2 = 0.f, a3 = 0.f;
  for (int kk = 0; kk < 1536; ++kk) {
    float w = Wd1[(size_t)kk*128 + t];
    a0 += sm[kk]*w; a1 += sm[1536 + kk]*w; a2 += sm[3072 + kk]*w; a3 += sm[4608 + kk]*w;
  }
  float b = bd1[t];
  sh[0][t] = lrelu(a0 + b); sh[1][t] = lrelu(a1 + b);
  sh[2][t] = lrelu(a2 + b); sh[3][t] = lrelu(a3 + b);
  __syncthreads();
  if (t < 8) {
    int gi = t >> 1, c = t & 1;
    float o = 0.f;
    for (int kk = 0; kk < 128; ++kk) o += sh[gi][kk]*Wd2[kk*2 + c];
    out[(size_t)(g0 + gi)*2 + c] = 1.f/(1.f + expf(-(o + bd2[c])));
  }
}

extern "C" void kernel_launch(void* const* d_in, const int* in_sizes, int n_in,
                              void* d_out, int out_size, void* d_ws, size_t ws_size,
                              hipStream_t stream) {
  const float* feat = (const float*)d_in[0];
  const float* adj  = (const float*)d_in[1];
  const float* W0 = (const float*)d_in[2];  const float* b0  = (const float*)d_in[3];
  const float* Ws0= (const float*)d_in[4];  const float* bs0 = (const float*)d_in[5];
  const float* W1 = (const float*)d_in[6];  const float* b1  = (const float*)d_in[7];
  const float* Ws1= (const float*)d_in[8];  const float* bs1 = (const float*)d_in[9];
  const float* W2 = (const float*)d_in[10]; const float* b2  = (const float*)d_in[11];
  const float* Ws2= (const float*)d_in[12]; const float* bs2 = (const float*)d_in[13];
  const float* Wd1= (const float*)d_in[14]; const float* bd1 = (const float*)d_in[15];
  const float* Wd2= (const float*)d_in[16]; const float* bd2 = (const float*)d_in[17];
  float* out = (float*)d_out;

  char* ws = (char*)d_ws;
  size_t off = 0;
  auto alloc = [&](size_t bytes) -> char* {
    char* p = ws + off; off += (bytes + 255) & ~(size_t)255; return p;
  };
  float* norm0 = (float*)alloc((size_t)GG*NN*4);
  unsigned long long* mask0 = (unsigned long long*)alloc((size_t)GG*NN*4*8);
  float* hs0   = (float*)alloc((size_t)GG*NN*4);
  float* merged= (float*)alloc((size_t)GG*1536*4);
  unsigned short* W0s = (unsigned short*)alloc((size_t)3*FF*DD*2);
  unsigned short* W1s = (unsigned short*)alloc((size_t)3*DD*DD*2);
  unsigned short* W2s = (unsigned short*)alloc((size_t)3*DD*DD*2);
  float* T0     = (float*)alloc((size_t)GG*NN*FF*4);        // 134 MB
  float* x_sel1 = (float*)alloc((size_t)GG*KS0*DD*4);       //  32 MB
  float* a1     = (float*)alloc((size_t)GG*KS0*KS0*4);      //   4 MB
  float* x_sel2 = (float*)alloc((size_t)GG*KS1*DD*4);       //  16 MB
  float* a2     = (float*)alloc((size_t)GG*KS1*KS1*4);      //   1 MB

  // ---- weight pre-split (one launch for all three) ----
  k_splitW_all<<<(FF*DD + 2*DD*DD)/256, 256, 0, stream>>>(W0, W1, W2, W0s, W1s, W2s);

  // ---- layer 0 ----
  k_maskrow<<<GG*NN/4, 256, 0, stream>>>(adj, norm0, mask0);
  k_spmm_s<<<4*GG, 256, 0, stream>>>(feat, mask0, norm0, T0);
  k_gemm0<<<GG*NN/128, 256, 0, stream>>>(T0, W0s, norm0, b0, Ws0, hs0);
  k_topk_sel0<<<GG, 256, 0, stream>>>(mask0, hs0, norm0, bs0, T0, W0, b0, x_sel1, a1, merged);

  // ---- layer 1 (fully fused per graph) ----
  k_fused1<<<GG, 256, 0, stream>>>(a1, x_sel1, W1s, b1, Ws1, bs1, x_sel2, a2, merged);

  // ---- layer 2 (fully fused per graph, LAST) ----
  k_fused2<<<GG, 256, 0, stream>>>(a2, x_sel2, W2s, b2, Ws2, bs2, merged);

  // ---- MLP head ----
  k_mlp<<<GG/4, 128, 0, stream>>>(merged, Wd1, bd1, Wd2, bd2, out);

  (void)in_sizes; (void)n_in; (void)out_size; (void)ws_size;
}